// Round 5
// baseline (224.588 us; speedup 1.0000x reference)
//
#include <hip/hip_runtime.h>
#include <hip/hip_bf16.h>
#include <math.h>

// DecoderSourceTarget: out[e] = sigmoid( dot( x[src[e], 0:128], x[dst[e], 128:256] ) )
// x: (100000, 256) fp32; edge_label_index: (2, 1e6) int; out: (1e6, 1) fp32.
//
// R5: decoder is at a ~3.5 TB/s pattern-dependent gather ceiling (R4: +4% from
// 2x MLP). Remaining levers: (a) cvt pass was 3.6 TB/s due to 64B-per-lane
// stride -> grid-stride float4 (unit lane stride, 8 indep loads/thread);
// (b) decoder 4 edges/group (8 gathers in flight) + fdot2 + float4 store.

#define HIDDEN 256
#define HALF   128

typedef _Float16 half8 __attribute__((ext_vector_type(8)));
typedef _Float16 half4 __attribute__((ext_vector_type(4)));
typedef _Float16 half2_t __attribute__((ext_vector_type(2)));

#define CVT_ITER 8

__global__ __launch_bounds__(256) void cvt_fp16_kernel(
    const float* __restrict__ x, _Float16* __restrict__ y, int n4)
{
    // grid-stride at float4 granularity: lane-unit stride, fully coalesced.
    int t = blockIdx.x * blockDim.x + threadIdx.x;
    int stride = gridDim.x * blockDim.x;

    const float4* x4 = (const float4*)x;
    half4* y4 = (half4*)y;

    float4 v[CVT_ITER];
    int idx[CVT_ITER];
    #pragma unroll
    for (int k = 0; k < CVT_ITER; ++k) {
        idx[k] = t + k * stride;
        v[k] = x4[idx[k]];          // 8 independent loads in flight
    }
    #pragma unroll
    for (int k = 0; k < CVT_ITER; ++k) {
        half4 h;
        h[0] = (_Float16)v[k].x;
        h[1] = (_Float16)v[k].y;
        h[2] = (_Float16)v[k].z;
        h[3] = (_Float16)v[k].w;
        y4[idx[k]] = h;
    }
}

__device__ __forceinline__ float dot8(half8 a, half8 b)
{
    float acc = 0.f;
    #pragma unroll
    for (int j = 0; j < 4; ++j) {
        half2_t aj = { a[2*j], a[2*j+1] };
        half2_t bj = { b[2*j], b[2*j+1] };
        acc = __builtin_amdgcn_fdot2(aj, bj, acc, false);
    }
    return acc;
}

__global__ __launch_bounds__(256) void decoder_fp16_kernel(
    const _Float16* __restrict__ y,
    const int* __restrict__ eidx,   // [2, n_edges] flattened
    float* __restrict__ out,
    int n_edges)
{
    int tid   = blockIdx.x * blockDim.x + threadIdx.x;
    int group = tid >> 4;       // 16 lanes per group, 4 edges per group
    int lane  = tid & 15;
    int e0 = group << 2;
    if (e0 >= n_edges) return;
    bool full = (e0 + 3) < n_edges;

    int4 se, de;
    if (full) {
        se = *(const int4*)(eidx + e0);
        de = *(const int4*)(eidx + n_edges + e0);
    } else {
        int s = eidx[e0], d = eidx[n_edges + e0];
        se = make_int4(s, s, s, s);
        de = make_int4(d, d, d, d);
        if (e0 + 1 < n_edges) { se.y = eidx[e0+1]; de.y = eidx[n_edges+e0+1]; }
        if (e0 + 2 < n_edges) { se.z = eidx[e0+2]; de.z = eidx[n_edges+e0+2]; }
    }

    // 8 independent 16B gathers — all issued before any use.
    half8 a0 = ((const half8*)(y + (size_t)se.x * HIDDEN))[lane];
    half8 b0 = ((const half8*)(y + (size_t)de.x * HIDDEN + HALF))[lane];
    half8 a1 = ((const half8*)(y + (size_t)se.y * HIDDEN))[lane];
    half8 b1 = ((const half8*)(y + (size_t)de.y * HIDDEN + HALF))[lane];
    half8 a2 = ((const half8*)(y + (size_t)se.z * HIDDEN))[lane];
    half8 b2 = ((const half8*)(y + (size_t)de.z * HIDDEN + HALF))[lane];
    half8 a3 = ((const half8*)(y + (size_t)se.w * HIDDEN))[lane];
    half8 b3 = ((const half8*)(y + (size_t)de.w * HIDDEN + HALF))[lane];

    float acc0 = dot8(a0, b0);
    float acc1 = dot8(a1, b1);
    float acc2 = dot8(a2, b2);
    float acc3 = dot8(a3, b3);

    #pragma unroll
    for (int off = 8; off > 0; off >>= 1) {
        acc0 += __shfl_down(acc0, off, 16);
        acc1 += __shfl_down(acc1, off, 16);
        acc2 += __shfl_down(acc2, off, 16);
        acc3 += __shfl_down(acc3, off, 16);
    }

    if (lane == 0) {
        float4 r;
        r.x = 1.0f / (1.0f + __expf(-acc0));
        r.y = 1.0f / (1.0f + __expf(-acc1));
        r.z = 1.0f / (1.0f + __expf(-acc2));
        r.w = 1.0f / (1.0f + __expf(-acc3));
        if (full) {
            ((float4*)out)[group] = r;   // e0 % 4 == 0 -> 16B aligned
        } else {
            out[e0] = r.x;
            if (e0 + 1 < n_edges) out[e0+1] = r.y;
            if (e0 + 2 < n_edges) out[e0+2] = r.z;
        }
    }
}

// fp32 fallback in case ws_size is too small for the fp16 table.
__global__ __launch_bounds__(256) void decoder_fp32_kernel(
    const float* __restrict__ x,
    const int* __restrict__ eidx,
    float* __restrict__ out,
    int n_edges)
{
    int tid  = blockIdx.x * blockDim.x + threadIdx.x;
    int edge = tid >> 5;
    int lane = tid & 31;
    if (edge >= n_edges) return;

    int s = eidx[edge];
    int d = eidx[n_edges + edge];

    const float4* sp = (const float4*)(x + (size_t)s * HIDDEN) + lane;
    const float4* dp = (const float4*)(x + (size_t)d * HIDDEN + HALF) + lane;

    float4 a = *sp;
    float4 b = *dp;
    float acc = a.x * b.x + a.y * b.y + a.z * b.z + a.w * b.w;

    #pragma unroll
    for (int off = 16; off > 0; off >>= 1)
        acc += __shfl_down(acc, off, 32);

    if (lane == 0) {
        out[edge] = 1.0f / (1.0f + __expf(-acc));
    }
}

extern "C" void kernel_launch(void* const* d_in, const int* in_sizes, int n_in,
                              void* d_out, int out_size, void* d_ws, size_t ws_size,
                              hipStream_t stream)
{
    const float* x    = (const float*)d_in[0];
    const int*   eidx = (const int*)d_in[1];
    float*       out  = (float*)d_out;

    int n_edges  = out_size;                  // 1,000,000
    int n_elems  = in_sizes[0];               // 25,600,000
    size_t need  = (size_t)n_elems * 2;       // fp16 table bytes

    if (ws_size >= need && (n_elems % (256 * CVT_ITER * 4)) == 0) {
        _Float16* y = (_Float16*)d_ws;

        int n4 = n_elems / 4;                       // float4 count
        int threads_total = n4 / CVT_ITER;          // exact: checked above
        cvt_fp16_kernel<<<threads_total / 256, 256, 0, stream>>>(x, y, n4);

        const int threads = 256;
        int groups = (n_edges + 3) / 4;             // 4 edges per 16-lane group
        long long total = (long long)groups * 16;
        int blocks = (int)((total + threads - 1) / threads);
        decoder_fp16_kernel<<<blocks, threads, 0, stream>>>(y, eidx, out, n_edges);
    } else {
        const int threads = 256;
        const int epb = threads / 32;
        int blocks = (n_edges + epb - 1) / epb;
        decoder_fp32_kernel<<<blocks, threads, 0, stream>>>(x, eidx, out, n_edges);
    }
}